// Round 2
// baseline (470.926 us; speedup 1.0000x reference)
//
#include <hip/hip_runtime.h>
#include <hip/hip_bf16.h>
#include <math.h>

#define BB 2
#define TT 2048
#define DM 1024
#define NH 16
#define HS 64
#define MM (BB*TT)   // 4096

typedef __attribute__((ext_vector_type(8))) short s16x8;
typedef __attribute__((ext_vector_type(4))) float f32x4;

#define MFMA16(a,b,c) __builtin_amdgcn_mfma_f32_16x16x32_bf16((a),(b),(c),0,0,0)

__device__ inline unsigned short f2bf(float f) {   // RNE
    union { float f; unsigned u; } x; x.f = f;
    unsigned r = x.u + 0x7fff + ((x.u >> 16) & 1);
    return (unsigned short)(r >> 16);
}
__device__ inline unsigned short f2bfr(float f) {  // round-half-up (cheap, hot path)
    union { float f; unsigned u; } x; x.f = f;
    return (unsigned short)((x.u + 0x8000u) >> 16);
}

// ---------------------------------------------------------------------------
// Kernel 1: Q/K/V projection.  C[m, h*64+hs] = sum_d x[m,d] * W[h,d,hs]
// 64x64 tile / block, 4 waves. Q is pre-scaled by 0.125*log2(e) (softmax in
// exp2 domain). V is written TRANSPOSED: Vt[b,h,hs,t].
// ---------------------------------------------------------------------------
__global__ __launch_bounds__(256) void proj_qkv_kernel(
    const float* __restrict__ q, const float* __restrict__ k,
    const float* __restrict__ v,
    const float* __restrict__ Wq, const float* __restrict__ Wk,
    const float* __restrict__ Wv,
    unsigned short* __restrict__ Qb, unsigned short* __restrict__ Kb,
    unsigned short* __restrict__ Vb)
{
    __shared__ __align__(16) short smem[7168];
    short* As = smem;            // [64][56]
    short* Bs = smem + 3584;     // [64][56]

    const int tid = threadIdx.x;
    const int l = tid & 63, w = tid >> 6;
    const int m0 = blockIdx.y * 64;
    const int h  = blockIdx.x;

    const float* x;  const float* W;  unsigned short* dst;
    if (blockIdx.z == 0)      { x = q; W = Wq; dst = Qb; }
    else if (blockIdx.z == 1) { x = k; W = Wk; dst = Kb; }
    else                      { x = v; W = Wv; dst = Vb; }
    const float* Wh = W + (size_t)h * DM * HS;

    f32x4 acc[4];
    for (int c = 0; c < 4; ++c)
        for (int j = 0; j < 4; ++j) acc[c][j] = 0.0f;

    const int arow = tid >> 2, acol = (tid & 3) * 8;
    const int bk = tid >> 3,  bn = (tid & 7) * 8;

    for (int k0 = 0; k0 < DM; k0 += 32) {
        const float* ap = x + (size_t)(m0 + arow) * DM + k0 + acol;
        float4 a0 = *(const float4*)ap;
        float4 a1 = *(const float4*)(ap + 4);
        s16x8 av;
        av[0] = (short)f2bf(a0.x); av[1] = (short)f2bf(a0.y);
        av[2] = (short)f2bf(a0.z); av[3] = (short)f2bf(a0.w);
        av[4] = (short)f2bf(a1.x); av[5] = (short)f2bf(a1.y);
        av[6] = (short)f2bf(a1.z); av[7] = (short)f2bf(a1.w);
        *(s16x8*)&As[arow * 56 + acol] = av;
        const float* bp = Wh + (size_t)(k0 + bk) * HS + bn;
        float4 b0 = *(const float4*)bp;
        float4 b1 = *(const float4*)(bp + 4);
        float bfv[8] = {b0.x, b0.y, b0.z, b0.w, b1.x, b1.y, b1.z, b1.w};
        #pragma unroll
        for (int i = 0; i < 8; ++i)
            Bs[(bn + i) * 56 + bk] = (short)f2bf(bfv[i]);
        __syncthreads();
        s16x8 afr = *(s16x8*)&As[(w * 16 + (l & 15)) * 56 + (l >> 4) * 8];
        #pragma unroll
        for (int c = 0; c < 4; ++c) {
            s16x8 bfr = *(s16x8*)&Bs[(c * 16 + (l & 15)) * 56 + (l >> 4) * 8];
            acc[c] = MFMA16(afr, bfr, acc[c]);
        }
        __syncthreads();
    }

    if (blockIdx.z != 2) {
        const float qscale = (blockIdx.z == 0) ? 0.18033688011112042f : 1.0f;
        #pragma unroll
        for (int c = 0; c < 4; ++c)
            #pragma unroll
            for (int j = 0; j < 4; ++j) {
                int row = m0 + w * 16 + (l >> 4) * 4 + j;
                int bb = row >> 11, tt = row & (TT - 1);
                int hs = c * 16 + (l & 15);
                dst[(((size_t)(bb * NH + h)) * TT + tt) * HS + hs] =
                    f2bf(acc[c][j] * qscale);
            }
    } else {
        // V: transpose through LDS, store Vt[b,h,hs,t]
        short* Tt = smem;        // [64][72], reuses As+Bs (all reads done)
        #pragma unroll
        for (int c = 0; c < 4; ++c)
            #pragma unroll
            for (int j = 0; j < 4; ++j)
                Tt[(c * 16 + (l & 15)) * 72 + w * 16 + (l >> 4) * 4 + j] =
                    (short)f2bf(acc[c][j]);
        __syncthreads();
        int hs = tid >> 2, toff = (tid & 3) * 16;
        s16x8 r0 = *(s16x8*)&Tt[hs * 72 + toff];
        s16x8 r1 = *(s16x8*)&Tt[hs * 72 + toff + 8];
        int bb = m0 >> 11, t0l = m0 & (TT - 1);
        unsigned short* vp = dst + (((size_t)(bb * NH + h)) * HS + hs) * TT + t0l + toff;
        *(s16x8*)vp = r0;
        *(s16x8*)(vp + 8) = r1;
    }
}

// ---------------------------------------------------------------------------
// Kernel 2: causal flash attention, v2.
// 4 waves/block, 32 q-rows/wave (2 row-frags), KVBLK=64.
// Q pre-scaled to exp2 domain. K frags direct global b128 loads; V frags
// direct b128 loads from transposed Vt. P re-fragmented via per-wave LDS.
// ---------------------------------------------------------------------------
template<bool MASKED>
__device__ __forceinline__ void flash_tile(
    int kv0, int q0, int r16, int g,
    const unsigned short* __restrict__ Kp,
    const unsigned short* __restrict__ Vp,
    short* __restrict__ Pw,
    const s16x8 (&qf)[2][2],
    float (&m_run)[2][4], float (&l_run)[2][4], f32x4 (&o)[2][4])
{
    f32x4 sacc[2][4];
    #pragma unroll
    for (int rf = 0; rf < 2; ++rf)
        #pragma unroll
        for (int c = 0; c < 4; ++c)
            #pragma unroll
            for (int j = 0; j < 4; ++j) sacc[rf][c][j] = 0.0f;

    #pragma unroll
    for (int c = 0; c < 4; ++c)
        #pragma unroll
        for (int s = 0; s < 2; ++s) {
            s16x8 kf = *(const s16x8*)(Kp + (size_t)(kv0 + c * 16 + r16) * HS + s * 32 + g * 8);
            sacc[0][c] = MFMA16(qf[0][s], kf, sacc[0][c]);
            sacc[1][c] = MFMA16(qf[1][s], kf, sacc[1][c]);
        }

    if (MASKED) {
        #pragma unroll
        for (int rf = 0; rf < 2; ++rf)
            #pragma unroll
            for (int c = 0; c < 4; ++c)
                #pragma unroll
                for (int j = 0; j < 4; ++j)
                    if (kv0 + c * 16 + r16 > q0 + rf * 16 + g * 4 + j)
                        sacc[rf][c][j] = -1e30f;
    }

    float corr[2][4];
    #pragma unroll
    for (int rf = 0; rf < 2; ++rf)
        #pragma unroll
        for (int j = 0; j < 4; ++j) {
            float pv0 = sacc[rf][0][j], pv1 = sacc[rf][1][j];
            float pv2 = sacc[rf][2][j], pv3 = sacc[rf][3][j];
            float pm = fmaxf(fmaxf(pv0, pv1), fmaxf(pv2, pv3));
            pm = fmaxf(pm, __shfl_xor(pm, 1));
            pm = fmaxf(pm, __shfl_xor(pm, 2));
            pm = fmaxf(pm, __shfl_xor(pm, 4));
            pm = fmaxf(pm, __shfl_xor(pm, 8));
            float mold = m_run[rf][j];
            float mn = fmaxf(mold, pm);
            float cr = __builtin_amdgcn_exp2f(mold - mn);
            m_run[rf][j] = mn;
            float e0 = __builtin_amdgcn_exp2f(pv0 - mn);
            float e1 = __builtin_amdgcn_exp2f(pv1 - mn);
            float e2 = __builtin_amdgcn_exp2f(pv2 - mn);
            float e3 = __builtin_amdgcn_exp2f(pv3 - mn);
            sacc[rf][0][j] = e0; sacc[rf][1][j] = e1;
            sacc[rf][2][j] = e2; sacc[rf][3][j] = e3;
            float ps = (e0 + e1) + (e2 + e3);
            ps += __shfl_xor(ps, 1);
            ps += __shfl_xor(ps, 2);
            ps += __shfl_xor(ps, 4);
            ps += __shfl_xor(ps, 8);
            l_run[rf][j] = l_run[rf][j] * cr + ps;
            corr[rf][j] = cr;
        }

    #pragma unroll
    for (int rf = 0; rf < 2; ++rf)
        #pragma unroll
        for (int c = 0; c < 4; ++c)
            #pragma unroll
            for (int j = 0; j < 4; ++j) o[rf][c][j] *= corr[rf][j];

    // P (D-layout) -> LDS -> A-layout fragments
    #pragma unroll
    for (int rf = 0; rf < 2; ++rf)
        #pragma unroll
        for (int c = 0; c < 4; ++c)
            #pragma unroll
            for (int j = 0; j < 4; ++j)
                Pw[(rf * 16 + g * 4 + j) * 72 + c * 16 + r16] =
                    (short)f2bfr(sacc[rf][c][j]);

    s16x8 pa[2][2];
    #pragma unroll
    for (int rf = 0; rf < 2; ++rf)
        #pragma unroll
        for (int s = 0; s < 2; ++s)
            pa[rf][s] = *(const s16x8*)&Pw[(rf * 16 + r16) * 72 + s * 32 + g * 8];

    #pragma unroll
    for (int c = 0; c < 4; ++c)
        #pragma unroll
        for (int s = 0; s < 2; ++s) {
            s16x8 vf = *(const s16x8*)(Vp + (size_t)(c * 16 + r16) * TT + kv0 + s * 32 + g * 8);
            o[0][c] = MFMA16(pa[0][s], vf, o[0][c]);
            o[1][c] = MFMA16(pa[1][s], vf, o[1][c]);
        }
}

__global__ __launch_bounds__(256) void flash2_kernel(
    const unsigned short* __restrict__ Qb,
    const unsigned short* __restrict__ Kb,
    const unsigned short* __restrict__ Vt,
    unsigned short* __restrict__ Ob)
{
    __shared__ __align__(16) short Pl[4][2304];   // per-wave [32][72]

    const int tid = threadIdx.x;
    const int l = tid & 63, w = tid >> 6;
    const int r16 = l & 15, g = l >> 4;

    // XCD-aware mapping: XCD = bid%8 owns 4 consecutive heads (K/V fit L2).
    // Heavy (large-q) blocks first.
    const int bid = blockIdx.x;
    const int xcd = bid & 7, idx = bid >> 3;
    const int bh = xcd * 4 + (idx & 3);
    const int qc = 31 - (idx >> 2);
    const int b = bh >> 4, h = bh & 15;
    const int q0 = qc * 128 + w * 32;

    const unsigned short* Qp = Qb + (size_t)bh * TT * HS;
    const unsigned short* Kp = Kb + (size_t)bh * TT * HS;
    const unsigned short* Vp = Vt + (size_t)bh * HS * TT;
    short* Pw = Pl[w];

    s16x8 qf[2][2];
    #pragma unroll
    for (int rf = 0; rf < 2; ++rf)
        #pragma unroll
        for (int s = 0; s < 2; ++s)
            qf[rf][s] = *(const s16x8*)(Qp + (size_t)(q0 + rf * 16 + r16) * HS + s * 32 + g * 8);

    float m_run[2][4], l_run[2][4];
    f32x4 o[2][4];
    #pragma unroll
    for (int rf = 0; rf < 2; ++rf)
        #pragma unroll
        for (int j = 0; j < 4; ++j) { m_run[rf][j] = -INFINITY; l_run[rf][j] = 0.0f; }
    #pragma unroll
    for (int rf = 0; rf < 2; ++rf)
        #pragma unroll
        for (int c = 0; c < 4; ++c)
            #pragma unroll
            for (int j = 0; j < 4; ++j) o[rf][c][j] = 0.0f;

    const int kvF = ((q0 + 1) >> 6) << 6;   // tiles with kv0+63 <= q0: unmasked
    for (int kv0 = 0; kv0 < kvF; kv0 += 64)
        flash_tile<false>(kv0, q0, r16, g, Kp, Vp, Pw, qf, m_run, l_run, o);
    for (int kv0 = kvF; kv0 < q0 + 32; kv0 += 64)
        flash_tile<true>(kv0, q0, r16, g, Kp, Vp, Pw, qf, m_run, l_run, o);

    #pragma unroll
    for (int rf = 0; rf < 2; ++rf)
        #pragma unroll
        for (int j = 0; j < 4; ++j) {
            float inv = 1.0f / l_run[rf][j];
            int t = q0 + rf * 16 + g * 4 + j;
            #pragma unroll
            for (int c = 0; c < 4; ++c)
                Ob[((size_t)(b * TT + t)) * DM + h * HS + c * 16 + r16] =
                    f2bfr(o[rf][c][j] * inv);
        }
}

// ---------------------------------------------------------------------------
// Kernel 3: out = O @ Wo + bo   (fp32 out)
// ---------------------------------------------------------------------------
__global__ __launch_bounds__(256) void out_proj_kernel(
    const unsigned short* __restrict__ Ob, const float* __restrict__ Wo,
    const float* __restrict__ bo, float* __restrict__ out)
{
    __shared__ __align__(16) short As[64 * 56];
    __shared__ __align__(16) short Bs[64 * 56];

    const int tid = threadIdx.x;
    const int l = tid & 63, w = tid >> 6;
    const int m0 = blockIdx.y * 64;
    const int n0 = blockIdx.x * 64;

    f32x4 acc[4];
    for (int c = 0; c < 4; ++c)
        for (int j = 0; j < 4; ++j) acc[c][j] = 0.0f;

    const int arow = tid >> 2, acol = (tid & 3) * 8;
    const int bk = tid >> 3,  bn = (tid & 7) * 8;

    for (int k0 = 0; k0 < DM; k0 += 32) {
        s16x8 av = *(const s16x8*)(Ob + (size_t)(m0 + arow) * DM + k0 + acol);
        *(s16x8*)&As[arow * 56 + acol] = av;
        const float* bp = Wo + (size_t)(k0 + bk) * DM + n0 + bn;
        float4 b0 = *(const float4*)bp;
        float4 b1 = *(const float4*)(bp + 4);
        float bfv[8] = {b0.x, b0.y, b0.z, b0.w, b1.x, b1.y, b1.z, b1.w};
        #pragma unroll
        for (int i = 0; i < 8; ++i)
            Bs[(bn + i) * 56 + bk] = (short)f2bf(bfv[i]);
        __syncthreads();
        s16x8 afr = *(s16x8*)&As[(w * 16 + (l & 15)) * 56 + (l >> 4) * 8];
        #pragma unroll
        for (int c = 0; c < 4; ++c) {
            s16x8 bfr = *(s16x8*)&Bs[(c * 16 + (l & 15)) * 56 + (l >> 4) * 8];
            acc[c] = MFMA16(afr, bfr, acc[c]);
        }
        __syncthreads();
    }

    #pragma unroll
    for (int c = 0; c < 4; ++c)
        #pragma unroll
        for (int j = 0; j < 4; ++j) {
            int row = m0 + w * 16 + (l >> 4) * 4 + j;
            int col = n0 + c * 16 + (l & 15);
            out[(size_t)row * DM + col] = acc[c][j] + bo[col];
        }
}

// ---------------------------------------------------------------------------
extern "C" void kernel_launch(void* const* d_in, const int* in_sizes, int n_in,
                              void* d_out, int out_size, void* d_ws, size_t ws_size,
                              hipStream_t stream) {
    const float* q  = (const float*)d_in[0];
    const float* k  = (const float*)d_in[1];
    const float* v  = (const float*)d_in[2];
    const float* Wq = (const float*)d_in[3];
    const float* Wk = (const float*)d_in[4];
    const float* Wv = (const float*)d_in[5];
    const float* Wo = (const float*)d_in[6];
    const float* bo = (const float*)d_in[7];
    float* out = (float*)d_out;

    const size_t QKV_ELEMS = (size_t)BB * NH * TT * HS;  // 4 Mi elems
    unsigned short* Qb = (unsigned short*)d_ws;
    unsigned short* Kb = Qb + QKV_ELEMS;
    unsigned short* Vt = Kb + QKV_ELEMS;                 // transposed [B,H,HS,T]
    unsigned short* Ob = Vt + QKV_ELEMS;                 // [M, D] bf16

    proj_qkv_kernel<<<dim3(NH, MM / 64, 3), 256, 0, stream>>>(
        q, k, v, Wq, Wk, Wv, Qb, Kb, Vt);
    flash2_kernel<<<dim3(1024), 256, 0, stream>>>(Qb, Kb, Vt, Ob);
    out_proj_kernel<<<dim3(DM / 64, MM / 64), 256, 0, stream>>>(Ob, Wo, bo, out);
}

// Round 3
// 302.150 us; speedup vs baseline: 1.5586x; 1.5586x over previous
//
#include <hip/hip_runtime.h>
#include <hip/hip_bf16.h>
#include <math.h>

#define BB 2
#define TT 2048
#define DM 1024
#define NH 16
#define HS 64
#define MM (BB*TT)   // 4096

typedef __attribute__((ext_vector_type(8))) short s16x8;
typedef __attribute__((ext_vector_type(4))) float f32x4;

#define MFMA16(a,b,c) __builtin_amdgcn_mfma_f32_16x16x32_bf16((a),(b),(c),0,0,0)

__device__ inline unsigned short f2bf(float f) {   // RNE
    union { float f; unsigned u; } x; x.f = f;
    unsigned r = x.u + 0x7fff + ((x.u >> 16) & 1);
    return (unsigned short)(r >> 16);
}
__device__ inline unsigned short f2bfr(float f) {  // round-half-up (cheap, hot path)
    union { float f; unsigned u; } x; x.f = f;
    return (unsigned short)((x.u + 0x8000u) >> 16);
}

// ---------------------------------------------------------------------------
// Kernel 1: Q/K/V projection.  C[m, h*64+hs] = sum_d x[m,d] * W[h,d,hs]
// 64x64 tile / block, 4 waves. Q is pre-scaled by 0.125*log2(e) (softmax in
// exp2 domain). V is written TRANSPOSED: Vt[b,h,hs,t].
// ---------------------------------------------------------------------------
__global__ __launch_bounds__(256) void proj_qkv_kernel(
    const float* __restrict__ q, const float* __restrict__ k,
    const float* __restrict__ v,
    const float* __restrict__ Wq, const float* __restrict__ Wk,
    const float* __restrict__ Wv,
    unsigned short* __restrict__ Qb, unsigned short* __restrict__ Kb,
    unsigned short* __restrict__ Vb)
{
    __shared__ __align__(16) short smem[7168];
    short* As = smem;            // [64][56]
    short* Bs = smem + 3584;     // [64][56]

    const int tid = threadIdx.x;
    const int l = tid & 63, w = tid >> 6;
    const int m0 = blockIdx.y * 64;
    const int h  = blockIdx.x;

    const float* x;  const float* W;  unsigned short* dst;
    if (blockIdx.z == 0)      { x = q; W = Wq; dst = Qb; }
    else if (blockIdx.z == 1) { x = k; W = Wk; dst = Kb; }
    else                      { x = v; W = Wv; dst = Vb; }
    const float* Wh = W + (size_t)h * DM * HS;

    f32x4 acc[4];
    for (int c = 0; c < 4; ++c)
        for (int j = 0; j < 4; ++j) acc[c][j] = 0.0f;

    const int arow = tid >> 2, acol = (tid & 3) * 8;
    const int bk = tid >> 3,  bn = (tid & 7) * 8;

    for (int k0 = 0; k0 < DM; k0 += 32) {
        const float* ap = x + (size_t)(m0 + arow) * DM + k0 + acol;
        float4 a0 = *(const float4*)ap;
        float4 a1 = *(const float4*)(ap + 4);
        s16x8 av;
        av[0] = (short)f2bf(a0.x); av[1] = (short)f2bf(a0.y);
        av[2] = (short)f2bf(a0.z); av[3] = (short)f2bf(a0.w);
        av[4] = (short)f2bf(a1.x); av[5] = (short)f2bf(a1.y);
        av[6] = (short)f2bf(a1.z); av[7] = (short)f2bf(a1.w);
        *(s16x8*)&As[arow * 56 + acol] = av;
        const float* bp = Wh + (size_t)(k0 + bk) * HS + bn;
        float4 b0 = *(const float4*)bp;
        float4 b1 = *(const float4*)(bp + 4);
        float bfv[8] = {b0.x, b0.y, b0.z, b0.w, b1.x, b1.y, b1.z, b1.w};
        #pragma unroll
        for (int i = 0; i < 8; ++i)
            Bs[(bn + i) * 56 + bk] = (short)f2bf(bfv[i]);
        __syncthreads();
        s16x8 afr = *(s16x8*)&As[(w * 16 + (l & 15)) * 56 + (l >> 4) * 8];
        #pragma unroll
        for (int c = 0; c < 4; ++c) {
            s16x8 bfr = *(s16x8*)&Bs[(c * 16 + (l & 15)) * 56 + (l >> 4) * 8];
            acc[c] = MFMA16(afr, bfr, acc[c]);
        }
        __syncthreads();
    }

    if (blockIdx.z != 2) {
        const float qscale = (blockIdx.z == 0) ? 0.18033688011112042f : 1.0f;
        #pragma unroll
        for (int c = 0; c < 4; ++c)
            #pragma unroll
            for (int j = 0; j < 4; ++j) {
                int row = m0 + w * 16 + (l >> 4) * 4 + j;
                int bb = row >> 11, tt = row & (TT - 1);
                int hs = c * 16 + (l & 15);
                dst[(((size_t)(bb * NH + h)) * TT + tt) * HS + hs] =
                    f2bf(acc[c][j] * qscale);
            }
    } else {
        // V: transpose through LDS, store Vt[b,h,hs,t]
        short* Tt = smem;        // [64][72], reuses As+Bs (all reads done)
        #pragma unroll
        for (int c = 0; c < 4; ++c)
            #pragma unroll
            for (int j = 0; j < 4; ++j)
                Tt[(c * 16 + (l & 15)) * 72 + w * 16 + (l >> 4) * 4 + j] =
                    (short)f2bf(acc[c][j]);
        __syncthreads();
        int hs = tid >> 2, toff = (tid & 3) * 16;
        s16x8 r0 = *(s16x8*)&Tt[hs * 72 + toff];
        s16x8 r1 = *(s16x8*)&Tt[hs * 72 + toff + 8];
        int bb = m0 >> 11, t0l = m0 & (TT - 1);
        unsigned short* vp = dst + (((size_t)(bb * NH + h)) * HS + hs) * TT + t0l + toff;
        *(s16x8*)vp = r0;
        *(s16x8*)(vp + 8) = r1;
    }
}

// ---------------------------------------------------------------------------
// Kernel 2: causal flash attention, v3.
// One wave owns a 16-row q-strip; each wave processes the strip PAIR
// (p, 127-p) sequentially -> uniform work per wave. 2048 waves, 512 blocks.
// K frags: direct b128 loads (L2-resident). V frags: b128 loads from Vt.
// P re-fragmented via small per-wave LDS tile [16][36].
// ---------------------------------------------------------------------------
template<bool MASKED>
__device__ __forceinline__ void flash_tile16(
    int kv0, int t0, int r16, int g,
    const unsigned short* __restrict__ Kp,
    const unsigned short* __restrict__ Vp,
    short* __restrict__ Pw,
    const s16x8 (&qf)[2],
    float (&m_run)[4], float (&l_run)[4], f32x4 (&o)[4])
{
    f32x4 sacc[2];
    #pragma unroll
    for (int c = 0; c < 2; ++c)
        #pragma unroll
        for (int j = 0; j < 4; ++j) sacc[c][j] = 0.0f;

    #pragma unroll
    for (int c = 0; c < 2; ++c)
        #pragma unroll
        for (int s = 0; s < 2; ++s) {
            s16x8 kf = *(const s16x8*)(Kp + (size_t)(kv0 + c * 16 + r16) * HS + s * 32 + g * 8);
            sacc[c] = MFMA16(qf[s], kf, sacc[c]);
        }

    if (MASKED) {
        #pragma unroll
        for (int c = 0; c < 2; ++c)
            #pragma unroll
            for (int j = 0; j < 4; ++j)
                if (kv0 + c * 16 + r16 > t0 + g * 4 + j)
                    sacc[c][j] = -1e30f;
    }

    float corr[4];
    #pragma unroll
    for (int j = 0; j < 4; ++j) {
        float pv0 = sacc[0][j], pv1 = sacc[1][j];
        float pm = fmaxf(pv0, pv1);
        pm = fmaxf(pm, __shfl_xor(pm, 1));
        pm = fmaxf(pm, __shfl_xor(pm, 2));
        pm = fmaxf(pm, __shfl_xor(pm, 4));
        pm = fmaxf(pm, __shfl_xor(pm, 8));
        float mold = m_run[j];
        float mn = fmaxf(mold, pm);
        float cr = __builtin_amdgcn_exp2f(mold - mn);
        m_run[j] = mn;
        float e0 = __builtin_amdgcn_exp2f(pv0 - mn);
        float e1 = __builtin_amdgcn_exp2f(pv1 - mn);
        sacc[0][j] = e0; sacc[1][j] = e1;
        float ps = e0 + e1;
        ps += __shfl_xor(ps, 1);
        ps += __shfl_xor(ps, 2);
        ps += __shfl_xor(ps, 4);
        ps += __shfl_xor(ps, 8);
        l_run[j] = l_run[j] * cr + ps;
        corr[j] = cr;
    }

    #pragma unroll
    for (int c = 0; c < 4; ++c)
        #pragma unroll
        for (int j = 0; j < 4; ++j) o[c][j] *= corr[j];

    // P (D-layout) -> LDS -> A-layout fragment
    #pragma unroll
    for (int c = 0; c < 2; ++c)
        #pragma unroll
        for (int j = 0; j < 4; ++j)
            Pw[(g * 4 + j) * 36 + c * 16 + r16] = (short)f2bfr(sacc[c][j]);

    s16x8 pa = *(const s16x8*)&Pw[r16 * 36 + g * 8];

    #pragma unroll
    for (int c = 0; c < 4; ++c) {
        s16x8 vf = *(const s16x8*)(Vp + (size_t)(c * 16 + r16) * TT + kv0 + g * 8);
        o[c] = MFMA16(pa, vf, o[c]);
    }
}

__device__ __forceinline__ void flash_strip16(
    int t0, int r16, int g,
    const unsigned short* __restrict__ Qp,
    const unsigned short* __restrict__ Kp,
    const unsigned short* __restrict__ Vp,
    unsigned short* __restrict__ Op,   // Ob + row-base for this (b,h)
    short* __restrict__ Pw)
{
    s16x8 qf[2];
    #pragma unroll
    for (int s = 0; s < 2; ++s)
        qf[s] = *(const s16x8*)(Qp + (size_t)(t0 + r16) * HS + s * 32 + g * 8);

    float m_run[4], l_run[4];
    f32x4 o[4];
    #pragma unroll
    for (int j = 0; j < 4; ++j) { m_run[j] = -INFINITY; l_run[j] = 0.0f; }
    #pragma unroll
    for (int c = 0; c < 4; ++c)
        #pragma unroll
        for (int j = 0; j < 4; ++j) o[c][j] = 0.0f;

    const int kvF = ((t0 + 1) >> 5) << 5;   // unmasked tiles: kv0 < kvF
    for (int kv0 = 0; kv0 < kvF; kv0 += 32)
        flash_tile16<false>(kv0, t0, r16, g, Kp, Vp, Pw, qf, m_run, l_run, o);
    for (int kv0 = kvF; kv0 < t0 + 16; kv0 += 32)
        flash_tile16<true>(kv0, t0, r16, g, Kp, Vp, Pw, qf, m_run, l_run, o);

    #pragma unroll
    for (int j = 0; j < 4; ++j) {
        float inv = 1.0f / l_run[j];
        int t = t0 + g * 4 + j;
        #pragma unroll
        for (int c = 0; c < 4; ++c)
            Op[(size_t)t * DM + c * 16 + r16] = f2bfr(o[c][j] * inv);
    }
}

__global__ __launch_bounds__(256) void flash3_kernel(
    const unsigned short* __restrict__ Qb,
    const unsigned short* __restrict__ Kb,
    const unsigned short* __restrict__ Vt,
    unsigned short* __restrict__ Ob)
{
    __shared__ __align__(16) short Pl[4][16 * 36];   // per-wave [16][36]

    const int tid = threadIdx.x;
    const int l = tid & 63, w = tid >> 6;
    const int r16 = l & 15, g = l >> 4;

    // global wave id -> (bh, strip pair). Natural round-robin puts
    // bh in {4x..4x+3} on XCD x (K+V = 2MB, fits 4MB L2).
    const int u = blockIdx.x * 4 + w;
    const int bh = u & 31;
    const int p  = u >> 5;          // 0..63
    const int b = bh >> 4, h = bh & 15;

    const unsigned short* Qp = Qb + (size_t)bh * TT * HS;
    const unsigned short* Kp = Kb + (size_t)bh * TT * HS;
    const unsigned short* Vp = Vt + (size_t)bh * HS * TT;
    unsigned short* Op = Ob + (size_t)b * TT * DM + h * HS;
    short* Pw = Pl[w];

    flash_strip16(16 * p,         r16, g, Qp, Kp, Vp, Op, Pw);
    flash_strip16(16 * (127 - p), r16, g, Qp, Kp, Vp, Op, Pw);
}

// ---------------------------------------------------------------------------
// Kernel 3: out = O @ Wo + bo   (fp32 out)
// ---------------------------------------------------------------------------
__global__ __launch_bounds__(256) void out_proj_kernel(
    const unsigned short* __restrict__ Ob, const float* __restrict__ Wo,
    const float* __restrict__ bo, float* __restrict__ out)
{
    __shared__ __align__(16) short As[64 * 56];
    __shared__ __align__(16) short Bs[64 * 56];

    const int tid = threadIdx.x;
    const int l = tid & 63, w = tid >> 6;
    const int m0 = blockIdx.y * 64;
    const int n0 = blockIdx.x * 64;

    f32x4 acc[4];
    for (int c = 0; c < 4; ++c)
        for (int j = 0; j < 4; ++j) acc[c][j] = 0.0f;

    const int arow = tid >> 2, acol = (tid & 3) * 8;
    const int bk = tid >> 3,  bn = (tid & 7) * 8;

    for (int k0 = 0; k0 < DM; k0 += 32) {
        s16x8 av = *(const s16x8*)(Ob + (size_t)(m0 + arow) * DM + k0 + acol);
        *(s16x8*)&As[arow * 56 + acol] = av;
        const float* bp = Wo + (size_t)(k0 + bk) * DM + n0 + bn;
        float4 b0 = *(const float4*)bp;
        float4 b1 = *(const float4*)(bp + 4);
        float bfv[8] = {b0.x, b0.y, b0.z, b0.w, b1.x, b1.y, b1.z, b1.w};
        #pragma unroll
        for (int i = 0; i < 8; ++i)
            Bs[(bn + i) * 56 + bk] = (short)f2bf(bfv[i]);
        __syncthreads();
        s16x8 afr = *(s16x8*)&As[(w * 16 + (l & 15)) * 56 + (l >> 4) * 8];
        #pragma unroll
        for (int c = 0; c < 4; ++c) {
            s16x8 bfr = *(s16x8*)&Bs[(c * 16 + (l & 15)) * 56 + (l >> 4) * 8];
            acc[c] = MFMA16(afr, bfr, acc[c]);
        }
        __syncthreads();
    }

    #pragma unroll
    for (int c = 0; c < 4; ++c)
        #pragma unroll
        for (int j = 0; j < 4; ++j) {
            int row = m0 + w * 16 + (l >> 4) * 4 + j;
            int col = n0 + c * 16 + (l & 15);
            out[(size_t)row * DM + col] = acc[c][j] + bo[col];
        }
}

// ---------------------------------------------------------------------------
extern "C" void kernel_launch(void* const* d_in, const int* in_sizes, int n_in,
                              void* d_out, int out_size, void* d_ws, size_t ws_size,
                              hipStream_t stream) {
    const float* q  = (const float*)d_in[0];
    const float* k  = (const float*)d_in[1];
    const float* v  = (const float*)d_in[2];
    const float* Wq = (const float*)d_in[3];
    const float* Wk = (const float*)d_in[4];
    const float* Wv = (const float*)d_in[5];
    const float* Wo = (const float*)d_in[6];
    const float* bo = (const float*)d_in[7];
    float* out = (float*)d_out;

    const size_t QKV_ELEMS = (size_t)BB * NH * TT * HS;  // 4 Mi elems
    unsigned short* Qb = (unsigned short*)d_ws;
    unsigned short* Kb = Qb + QKV_ELEMS;
    unsigned short* Vt = Kb + QKV_ELEMS;                 // transposed [B,H,HS,T]
    unsigned short* Ob = Vt + QKV_ELEMS;                 // [M, D] bf16

    proj_qkv_kernel<<<dim3(NH, MM / 64, 3), 256, 0, stream>>>(
        q, k, v, Wq, Wk, Wv, Qb, Kb, Vt);
    flash3_kernel<<<dim3(512), 256, 0, stream>>>(Qb, Kb, Vt, Ob);
    out_proj_kernel<<<dim3(DM / 64, MM / 64), 256, 0, stream>>>(Ob, Wo, bo, out);
}

// Round 4
// 227.367 us; speedup vs baseline: 2.0712x; 1.3289x over previous
//
#include <hip/hip_runtime.h>
#include <hip/hip_bf16.h>
#include <math.h>

#define BB 2
#define TT 2048
#define DM 1024
#define NH 16
#define HS 64
#define MM (BB*TT)   // 4096

typedef __attribute__((ext_vector_type(8))) short s16x8;
typedef __attribute__((ext_vector_type(4))) float f32x4;

#define MFMA16(a,b,c) __builtin_amdgcn_mfma_f32_16x16x32_bf16((a),(b),(c),0,0,0)

__device__ inline unsigned short f2bf(float f) {   // RNE
    union { float f; unsigned u; } x; x.f = f;
    unsigned r = x.u + 0x7fff + ((x.u >> 16) & 1);
    return (unsigned short)(r >> 16);
}
__device__ inline unsigned short f2bfr(float f) {  // round-half-up (hot path)
    union { float f; unsigned u; } x; x.f = f;
    return (unsigned short)((x.u + 0x8000u) >> 16);
}

__device__ __forceinline__ void gload16(const void* g, void* l) {
    __builtin_amdgcn_global_load_lds(
        (const __attribute__((address_space(1))) unsigned int*)g,
        (__attribute__((address_space(3))) unsigned int*)l, 16, 0, 0);
}

// ---------------------------------------------------------------------------
// Kernel 0: weight convert+transpose.  Wt[n][d] (bf16) from W[h,d,hs] fp32
// (n = h*64+hs), or from Wo[d][n] when wo_mode=1.
// ---------------------------------------------------------------------------
__global__ __launch_bounds__(256) void cvt_w_kernel(
    const float* __restrict__ W0, const float* __restrict__ W1,
    const float* __restrict__ W2, unsigned short* __restrict__ dst, int wo_mode)
{
    __shared__ __align__(16) short Tt[64 * 72];
    const int t = threadIdx.x;
    const int d0 = blockIdx.x * 64;
    const int h  = blockIdx.y;
    const int z  = blockIdx.z;
    const float* W = (z == 0) ? W0 : (z == 1) ? W1 : W2;
    unsigned short* dz = dst + (size_t)z * DM * DM;

    #pragma unroll
    for (int it = 0; it < 16; ++it) {
        int dl = it * 4 + (t >> 6);
        int hs = t & 63;
        float vv = wo_mode ? W[(size_t)(d0 + dl) * DM + h * 64 + hs]
                           : W[(size_t)h * DM * HS + (size_t)(d0 + dl) * HS + hs];
        Tt[hs * 72 + dl] = (short)f2bf(vv);
    }
    __syncthreads();
    int hs = t >> 2, doff = (t & 3) * 16;
    s16x8 r0 = *(s16x8*)&Tt[hs * 72 + doff];
    s16x8 r1 = *(s16x8*)&Tt[hs * 72 + doff + 8];
    unsigned short* op = dz + (size_t)(h * 64 + hs) * DM + d0 + doff;
    *(s16x8*)op = r0;
    *(s16x8*)(op + 8) = r1;
}

// ---------------------------------------------------------------------------
// Kernel 1: Q/K/V projection GEMM, m97-structure.
// 128x128 tile, BK=32, 4 waves (2x2, 64x64 each). A fp32 via global_load_lds
// (bf16-convert at fragment load), B bf16 from pre-transposed Wt.
// XOR-swizzled LDS (pre-swizzled global src + swizzled read; linear dest).
// ---------------------------------------------------------------------------
__global__ __launch_bounds__(256) void proj_gemm_kernel(
    const float* __restrict__ q, const float* __restrict__ k,
    const float* __restrict__ v, const unsigned short* __restrict__ Wt,
    unsigned short* __restrict__ Qb, unsigned short* __restrict__ Kb,
    unsigned short* __restrict__ Vt)
{
    __shared__ __align__(16) float As[128 * 32];           // 16 KB
    __shared__ __align__(16) unsigned short Bs[128 * 32];  // 8 KB, [n][k]

    const int tid = threadIdx.x;
    const int l = tid & 63, w = tid >> 6;
    const int wr = w >> 1, wc = w & 1;
    const int g = l >> 4, r16 = l & 15;
    const int z = blockIdx.z;
    const int m0 = blockIdx.y * 128;
    const int n0 = blockIdx.x * 128;

    const float* x = (z == 0) ? q : (z == 1) ? k : v;
    const unsigned short* Wz = Wt + (size_t)z * DM * DM;

    // staging addresses (A: 1024 16B-chunks in 4 passes; B: 512 in 2)
    const float* aS[4]; float* aD[4];
    #pragma unroll
    for (int p = 0; p < 4; ++p) {
        int qid = p * 256 + tid;
        int row = qid >> 3, gl = qid & 7;
        int col = ((gl ^ (row & 7)) * 4);
        aS[p] = x + (size_t)(m0 + row) * DM + col;
        aD[p] = As + qid * 4;
    }
    const unsigned short* bS[2]; unsigned short* bD[2];
    #pragma unroll
    for (int p = 0; p < 2; ++p) {
        int qid = p * 256 + tid;
        int row = qid >> 2, gl = qid & 3;
        int col = ((gl ^ ((row >> 1) & 3)) * 8);
        bS[p] = Wz + (size_t)(n0 + row) * DM + col;
        bD[p] = Bs + qid * 8;
    }

    // fragment LDS offsets (k0-invariant)
    int aoff[4][2], boff[4];
    #pragma unroll
    for (int i = 0; i < 4; ++i) {
        int row = wr * 64 + i * 16 + r16;
        int s = row & 7;
        aoff[i][0] = row * 32 + ((2 * g) ^ s) * 4;
        aoff[i][1] = row * 32 + ((2 * g + 1) ^ s) * 4;
    }
    #pragma unroll
    for (int c = 0; c < 4; ++c) {
        int row = wc * 64 + c * 16 + r16;
        boff[c] = row * 32 + (g ^ ((row >> 1) & 3)) * 8;
    }

    f32x4 acc[4][4];
    #pragma unroll
    for (int i = 0; i < 4; ++i)
        #pragma unroll
        for (int c = 0; c < 4; ++c)
            #pragma unroll
            for (int j = 0; j < 4; ++j) acc[i][c][j] = 0.0f;

    for (int k0 = 0; k0 < DM; k0 += 32) {
        #pragma unroll
        for (int p = 0; p < 4; ++p) gload16(aS[p] + k0, aD[p]);
        #pragma unroll
        for (int p = 0; p < 2; ++p) gload16(bS[p] + k0, bD[p]);
        __syncthreads();

        s16x8 af[4], bf[4];
        #pragma unroll
        for (int i = 0; i < 4; ++i) {
            float4 lo = *(const float4*)&As[aoff[i][0]];
            float4 hi = *(const float4*)&As[aoff[i][1]];
            union { s16x8 v; __hip_bfloat162 h[4]; } cv;
            cv.h[0] = __float22bfloat162_rn(make_float2(lo.x, lo.y));
            cv.h[1] = __float22bfloat162_rn(make_float2(lo.z, lo.w));
            cv.h[2] = __float22bfloat162_rn(make_float2(hi.x, hi.y));
            cv.h[3] = __float22bfloat162_rn(make_float2(hi.z, hi.w));
            af[i] = cv.v;
        }
        #pragma unroll
        for (int c = 0; c < 4; ++c) bf[c] = *(const s16x8*)&Bs[boff[c]];
        #pragma unroll
        for (int i = 0; i < 4; ++i)
            #pragma unroll
            for (int c = 0; c < 4; ++c)
                acc[i][c] = MFMA16(af[i], bf[c], acc[i][c]);
        __syncthreads();
    }

    const int h = (n0 >> 6) + wc;
    if (z != 2) {
        unsigned short* dst = (z == 0) ? Qb : Kb;
        const float sc = (z == 0) ? 0.18033688011112042f : 1.0f;  // 0.125*log2e
        #pragma unroll
        for (int i = 0; i < 4; ++i)
            #pragma unroll
            for (int j = 0; j < 4; ++j) {
                int row = m0 + wr * 64 + i * 16 + g * 4 + j;
                int bb = row >> 11, tt = row & (TT - 1);
                size_t rb = (((size_t)(bb * NH + h)) * TT + tt) * HS;
                #pragma unroll
                for (int c = 0; c < 4; ++c)
                    dst[rb + c * 16 + r16] = f2bf(acc[i][c][j] * sc);
            }
    } else {
        // V transposed: Vt[(b*NH+h)*HS + hs][t], pack 4 consecutive t
        #pragma unroll
        for (int i = 0; i < 4; ++i) {
            int row0 = m0 + wr * 64 + i * 16 + g * 4;
            int bb = row0 >> 11, tt0 = row0 & (TT - 1);
            #pragma unroll
            for (int c = 0; c < 4; ++c) {
                int hs = c * 16 + r16;
                union { unsigned long long u; unsigned short s[4]; } pk;
                #pragma unroll
                for (int j = 0; j < 4; ++j) pk.s[j] = f2bf(acc[i][c][j]);
                *(unsigned long long*)&Vt[(((size_t)(bb * NH + h)) * HS + hs) * TT + tt0] = pk.u;
            }
        }
    }
}

// ---------------------------------------------------------------------------
// Kernel 3: out = Ob @ Wo + bo (fp32 out). Same structure, bf16 A.
// ---------------------------------------------------------------------------
__global__ __launch_bounds__(256) void out_gemm_kernel(
    const unsigned short* __restrict__ Ob, const unsigned short* __restrict__ Wot,
    const float* __restrict__ bo, float* __restrict__ out)
{
    __shared__ __align__(16) unsigned short As2[128 * 32];
    __shared__ __align__(16) unsigned short Bs2[128 * 32];

    const int tid = threadIdx.x;
    const int l = tid & 63, w = tid >> 6;
    const int wr = w >> 1, wc = w & 1;
    const int g = l >> 4, r16 = l & 15;
    const int m0 = blockIdx.y * 128;
    const int n0 = blockIdx.x * 128;

    const unsigned short* aS[2]; unsigned short* aD[2];
    const unsigned short* bS[2]; unsigned short* bD[2];
    #pragma unroll
    for (int p = 0; p < 2; ++p) {
        int qid = p * 256 + tid;
        int row = qid >> 2, gl = qid & 3;
        int col = ((gl ^ ((row >> 1) & 3)) * 8);
        aS[p] = Ob + (size_t)(m0 + row) * DM + col;
        aD[p] = As2 + qid * 8;
        bS[p] = Wot + (size_t)(n0 + row) * DM + col;
        bD[p] = Bs2 + qid * 8;
    }

    int aoff[4], boff[4];
    #pragma unroll
    for (int i = 0; i < 4; ++i) {
        int row = wr * 64 + i * 16 + r16;
        aoff[i] = row * 32 + (g ^ ((row >> 1) & 3)) * 8;
    }
    #pragma unroll
    for (int c = 0; c < 4; ++c) {
        int row = wc * 64 + c * 16 + r16;
        boff[c] = row * 32 + (g ^ ((row >> 1) & 3)) * 8;
    }

    f32x4 acc[4][4];
    #pragma unroll
    for (int i = 0; i < 4; ++i)
        #pragma unroll
        for (int c = 0; c < 4; ++c)
            #pragma unroll
            for (int j = 0; j < 4; ++j) acc[i][c][j] = 0.0f;

    for (int k0 = 0; k0 < DM; k0 += 32) {
        #pragma unroll
        for (int p = 0; p < 2; ++p) gload16(aS[p] + k0, aD[p]);
        #pragma unroll
        for (int p = 0; p < 2; ++p) gload16(bS[p] + k0, bD[p]);
        __syncthreads();

        s16x8 af[4], bf[4];
        #pragma unroll
        for (int i = 0; i < 4; ++i) af[i] = *(const s16x8*)&As2[aoff[i]];
        #pragma unroll
        for (int c = 0; c < 4; ++c) bf[c] = *(const s16x8*)&Bs2[boff[c]];
        #pragma unroll
        for (int i = 0; i < 4; ++i)
            #pragma unroll
            for (int c = 0; c < 4; ++c)
                acc[i][c] = MFMA16(af[i], bf[c], acc[i][c]);
        __syncthreads();
    }

    #pragma unroll
    for (int i = 0; i < 4; ++i)
        #pragma unroll
        for (int j = 0; j < 4; ++j) {
            int row = m0 + wr * 64 + i * 16 + g * 4 + j;
            #pragma unroll
            for (int c = 0; c < 4; ++c) {
                int col = n0 + wc * 64 + c * 16 + r16;
                out[(size_t)row * DM + col] = acc[i][c][j] + bo[col];
            }
        }
}

// ---------------------------------------------------------------------------
// Kernel 2: causal flash attention (unchanged from round 3).
// ---------------------------------------------------------------------------
template<bool MASKED>
__device__ __forceinline__ void flash_tile16(
    int kv0, int t0, int r16, int g,
    const unsigned short* __restrict__ Kp,
    const unsigned short* __restrict__ Vp,
    short* __restrict__ Pw,
    const s16x8 (&qf)[2],
    float (&m_run)[4], float (&l_run)[4], f32x4 (&o)[4])
{
    f32x4 sacc[2];
    #pragma unroll
    for (int c = 0; c < 2; ++c)
        #pragma unroll
        for (int j = 0; j < 4; ++j) sacc[c][j] = 0.0f;

    #pragma unroll
    for (int c = 0; c < 2; ++c)
        #pragma unroll
        for (int s = 0; s < 2; ++s) {
            s16x8 kf = *(const s16x8*)(Kp + (size_t)(kv0 + c * 16 + r16) * HS + s * 32 + g * 8);
            sacc[c] = MFMA16(qf[s], kf, sacc[c]);
        }

    if (MASKED) {
        #pragma unroll
        for (int c = 0; c < 2; ++c)
            #pragma unroll
            for (int j = 0; j < 4; ++j)
                if (kv0 + c * 16 + r16 > t0 + g * 4 + j)
                    sacc[c][j] = -1e30f;
    }

    float corr[4];
    #pragma unroll
    for (int j = 0; j < 4; ++j) {
        float pv0 = sacc[0][j], pv1 = sacc[1][j];
        float pm = fmaxf(pv0, pv1);
        pm = fmaxf(pm, __shfl_xor(pm, 1));
        pm = fmaxf(pm, __shfl_xor(pm, 2));
        pm = fmaxf(pm, __shfl_xor(pm, 4));
        pm = fmaxf(pm, __shfl_xor(pm, 8));
        float mold = m_run[j];
        float mn = fmaxf(mold, pm);
        float cr = __builtin_amdgcn_exp2f(mold - mn);
        m_run[j] = mn;
        float e0 = __builtin_amdgcn_exp2f(pv0 - mn);
        float e1 = __builtin_amdgcn_exp2f(pv1 - mn);
        sacc[0][j] = e0; sacc[1][j] = e1;
        float ps = e0 + e1;
        ps += __shfl_xor(ps, 1);
        ps += __shfl_xor(ps, 2);
        ps += __shfl_xor(ps, 4);
        ps += __shfl_xor(ps, 8);
        l_run[j] = l_run[j] * cr + ps;
        corr[j] = cr;
    }

    #pragma unroll
    for (int c = 0; c < 4; ++c)
        #pragma unroll
        for (int j = 0; j < 4; ++j) o[c][j] *= corr[j];

    #pragma unroll
    for (int c = 0; c < 2; ++c)
        #pragma unroll
        for (int j = 0; j < 4; ++j)
            Pw[(g * 4 + j) * 36 + c * 16 + r16] = (short)f2bfr(sacc[c][j]);

    s16x8 pa = *(const s16x8*)&Pw[r16 * 36 + g * 8];

    #pragma unroll
    for (int c = 0; c < 4; ++c) {
        s16x8 vf = *(const s16x8*)(Vp + (size_t)(c * 16 + r16) * TT + kv0 + g * 8);
        o[c] = MFMA16(pa, vf, o[c]);
    }
}

__device__ __forceinline__ void flash_strip16(
    int t0, int r16, int g,
    const unsigned short* __restrict__ Qp,
    const unsigned short* __restrict__ Kp,
    const unsigned short* __restrict__ Vp,
    unsigned short* __restrict__ Op,
    short* __restrict__ Pw)
{
    s16x8 qf[2];
    #pragma unroll
    for (int s = 0; s < 2; ++s)
        qf[s] = *(const s16x8*)(Qp + (size_t)(t0 + r16) * HS + s * 32 + g * 8);

    float m_run[4], l_run[4];
    f32x4 o[4];
    #pragma unroll
    for (int j = 0; j < 4; ++j) { m_run[j] = -INFINITY; l_run[j] = 0.0f; }
    #pragma unroll
    for (int c = 0; c < 4; ++c)
        #pragma unroll
        for (int j = 0; j < 4; ++j) o[c][j] = 0.0f;

    const int kvF = ((t0 + 1) >> 5) << 5;
    for (int kv0 = 0; kv0 < kvF; kv0 += 32)
        flash_tile16<false>(kv0, t0, r16, g, Kp, Vp, Pw, qf, m_run, l_run, o);
    for (int kv0 = kvF; kv0 < t0 + 16; kv0 += 32)
        flash_tile16<true>(kv0, t0, r16, g, Kp, Vp, Pw, qf, m_run, l_run, o);

    #pragma unroll
    for (int j = 0; j < 4; ++j) {
        float inv = 1.0f / l_run[j];
        int t = t0 + g * 4 + j;
        #pragma unroll
        for (int c = 0; c < 4; ++c)
            Op[(size_t)t * DM + c * 16 + r16] = f2bfr(o[c][j] * inv);
    }
}

__global__ __launch_bounds__(256) void flash3_kernel(
    const unsigned short* __restrict__ Qb,
    const unsigned short* __restrict__ Kb,
    const unsigned short* __restrict__ Vt,
    unsigned short* __restrict__ Ob)
{
    __shared__ __align__(16) short Pl[4][16 * 36];

    const int tid = threadIdx.x;
    const int l = tid & 63, w = tid >> 6;
    const int r16 = l & 15, g = l >> 4;

    const int u = blockIdx.x * 4 + w;
    const int bh = u & 31;
    const int p  = u >> 5;
    const int b = bh >> 4, h = bh & 15;

    const unsigned short* Qp = Qb + (size_t)bh * TT * HS;
    const unsigned short* Kp = Kb + (size_t)bh * TT * HS;
    const unsigned short* Vp = Vt + (size_t)bh * HS * TT;
    unsigned short* Op = Ob + (size_t)b * TT * DM + h * HS;
    short* Pw = Pl[w];

    flash_strip16(16 * p,         r16, g, Qp, Kp, Vp, Op, Pw);
    flash_strip16(16 * (127 - p), r16, g, Qp, Kp, Vp, Op, Pw);
}

// ---------------------------------------------------------------------------
extern "C" void kernel_launch(void* const* d_in, const int* in_sizes, int n_in,
                              void* d_out, int out_size, void* d_ws, size_t ws_size,
                              hipStream_t stream) {
    const float* q  = (const float*)d_in[0];
    const float* k  = (const float*)d_in[1];
    const float* v  = (const float*)d_in[2];
    const float* Wq = (const float*)d_in[3];
    const float* Wk = (const float*)d_in[4];
    const float* Wv = (const float*)d_in[5];
    const float* Wo = (const float*)d_in[6];
    const float* bo = (const float*)d_in[7];
    float* out = (float*)d_out;

    const size_t QKV_ELEMS = (size_t)BB * NH * TT * HS;  // 4 Mi elems (8 MB)
    unsigned short* Qb = (unsigned short*)d_ws;
    unsigned short* Kb = Qb + QKV_ELEMS;
    unsigned short* Vt = Kb + QKV_ELEMS;                 // [B,H,HS,T]
    unsigned short* R4 = Vt + QKV_ELEMS;                 // 8 MB shared region
    unsigned short* Wt = R4;                             // Wq/k/v^T (6 MB), pre-flash
    unsigned short* Ob = R4;                             // flash out, overwrites Wt
    unsigned short* Wot = Qb;                            // Wo^T (2 MB), post-flash

    cvt_w_kernel<<<dim3(16, 16, 3), 256, 0, stream>>>(Wq, Wk, Wv, Wt, 0);
    proj_gemm_kernel<<<dim3(8, 32, 3), 256, 0, stream>>>(q, k, v, Wt, Qb, Kb, Vt);
    flash3_kernel<<<dim3(512), 256, 0, stream>>>(Qb, Kb, Vt, Ob);
    cvt_w_kernel<<<dim3(16, 16, 1), 256, 0, stream>>>(Wo, Wo, Wo, Wot, 1);
    out_gemm_kernel<<<dim3(8, 32), 256, 0, stream>>>(Ob, Wot, bo, out);
}